// Round 3
// baseline (164.138 us; speedup 1.0000x reference)
//
#include <hip/hip_runtime.h>

// Embedding gather: out[i, :] = weight[idx[i], :]
// idx: [8*4096] int32, weight: [50257, 512] fp32, out: [8*4096, 512] fp32.
//
// v3: exactly-resident persistent layout.
//  - 2048 blocks x 256 thr = 8192 waves = 256 CU x 32 waves: ONE occupancy
//    generation (v2 had 16384 waves -> 2 generations of ramp/drain).
//  - wave w owns rows 4w..4w+3: row0 is wave-uniform -> idx loads scalarize
//    to s_load; 8 independent weight loads (2 per row, each a contiguous
//    1 KiB wave segment) in flight per wave; 8 NT streaming stores.
//  - __launch_bounds__(256, 8): pin <=64 VGPR so all 8192 waves co-resident.

#define EMBED_F4 128          // 512 floats / 4
#define N_IDX    (8 * 4096)   // 32768 rows
#define ROWS_PER_WAVE 4
#define BLOCK 256
#define GRID  ((N_IDX / ROWS_PER_WAVE) * 64 / BLOCK)   // 2048 blocks

typedef float f4 __attribute__((ext_vector_type(4)));

__global__ __launch_bounds__(BLOCK, 8) void Embedding_60327110640045_kernel(
    const int* __restrict__ idx,
    const f4* __restrict__ weight,   // [50257 * 128] f4
    f4* __restrict__ out)            // [32768 * 128] f4
{
    int tid  = blockIdx.x * BLOCK + threadIdx.x;
    int wave = tid >> 6;                  // 0..8191
    int lane = tid & 63;                  // f4 index within row half
    int row0 = wave * ROWS_PER_WAVE;      // wave-uniform

    // 4 row indices (wave-uniform addresses -> scalarizable)
    int r0 = idx[row0 + 0];
    int r1 = idx[row0 + 1];
    int r2 = idx[row0 + 2];
    int r3 = idx[row0 + 3];

    const f4* __restrict__ s0 = weight + (size_t)r0 * EMBED_F4 + lane;
    const f4* __restrict__ s1 = weight + (size_t)r1 * EMBED_F4 + lane;
    const f4* __restrict__ s2 = weight + (size_t)r2 * EMBED_F4 + lane;
    const f4* __restrict__ s3 = weight + (size_t)r3 * EMBED_F4 + lane;

    // 8 independent loads in flight; each covers a contiguous 1 KiB segment
    // (64 lanes x 16 B) of one weight row.
    f4 a0 = s0[0], b0 = s0[64];
    f4 a1 = s1[0], b1 = s1[64];
    f4 a2 = s2[0], b2 = s2[64];
    f4 a3 = s3[0], b3 = s3[64];

    f4* __restrict__ d = out + (size_t)row0 * EMBED_F4 + lane;
    __builtin_nontemporal_store(a0, d + 0 * EMBED_F4);
    __builtin_nontemporal_store(b0, d + 0 * EMBED_F4 + 64);
    __builtin_nontemporal_store(a1, d + 1 * EMBED_F4);
    __builtin_nontemporal_store(b1, d + 1 * EMBED_F4 + 64);
    __builtin_nontemporal_store(a2, d + 2 * EMBED_F4);
    __builtin_nontemporal_store(b2, d + 2 * EMBED_F4 + 64);
    __builtin_nontemporal_store(a3, d + 3 * EMBED_F4);
    __builtin_nontemporal_store(b3, d + 3 * EMBED_F4 + 64);
}

extern "C" void kernel_launch(void* const* d_in, const int* in_sizes, int n_in,
                              void* d_out, int out_size, void* d_ws, size_t ws_size,
                              hipStream_t stream) {
    const int* idx    = (const int*)d_in[0];
    const f4*  weight = (const f4*)d_in[1];
    f4*        out    = (f4*)d_out;

    Embedding_60327110640045_kernel<<<GRID, BLOCK, 0, stream>>>(idx, weight, out);
}